// Round 6
// baseline (488.390 us; speedup 1.0000x reference)
//
#include <hip/hip_runtime.h>

// N=32768 rows, K=8192 codes, D=256, fp32 in, int32 out.
constexpr int D_DIM   = 256;
constexpr int N_ROWS  = 32768;
constexpr int K_CODES = 8192;

// ---- fast path (pre-converted, blocked layout) ----
constexpr int BM     = 128;             // rows per block
constexpr int BN     = 256;             // codes per tile
constexpr int STRIP  = 4096;            // codes per block (2 strips)
constexpr int NSTRIP = K_CODES / STRIP; // 2
constexpr int NCT    = STRIP / BN;      // 16
constexpr int NDC    = 16;              // 16 chunks of BK=16 dims (2 granule layers)
constexpr int NIT    = NCT * NDC;       // 256 flat pipeline iterations

typedef _Float16 f16x8  __attribute__((ext_vector_type(8)));
typedef __fp16   fp16x2 __attribute__((ext_vector_type(2)));
typedef float    f32x16 __attribute__((ext_vector_type(16)));

#define MFMA32(a, b, c) __builtin_amdgcn_mfma_f32_32x32x16_f16(a, b, c, 0, 0, 0)

// Split one granule (8 fp32) into fp16 hi (pkrtz, RTZ) + fp16 lo (residual).
__device__ __forceinline__ void cvt_granule(const float4 a, const float4 b,
                                            uint4& hi, uint4& lo) {
    fp16x2 h0 = __builtin_amdgcn_cvt_pkrtz(a.x, a.y);
    fp16x2 h1 = __builtin_amdgcn_cvt_pkrtz(a.z, a.w);
    fp16x2 h2 = __builtin_amdgcn_cvt_pkrtz(b.x, b.y);
    fp16x2 h3 = __builtin_amdgcn_cvt_pkrtz(b.z, b.w);
    fp16x2 l0 = __builtin_amdgcn_cvt_pkrtz(a.x - (float)h0.x, a.y - (float)h0.y);
    fp16x2 l1 = __builtin_amdgcn_cvt_pkrtz(a.z - (float)h1.x, a.w - (float)h1.y);
    fp16x2 l2 = __builtin_amdgcn_cvt_pkrtz(b.x - (float)h2.x, b.y - (float)h2.y);
    fp16x2 l3 = __builtin_amdgcn_cvt_pkrtz(b.z - (float)h3.x, b.w - (float)h3.y);
    hi = make_uint4(__builtin_bit_cast(unsigned, h0), __builtin_bit_cast(unsigned, h1),
                    __builtin_bit_cast(unsigned, h2), __builtin_bit_cast(unsigned, h3));
    lo = make_uint4(__builtin_bit_cast(unsigned, l0), __builtin_bit_cast(unsigned, l1),
                    __builtin_bit_cast(unsigned, l2), __builtin_bit_cast(unsigned, l3));
}

// async global->LDS, 16 B per lane; lds dst is wave-uniform base + lane*16.
__device__ __forceinline__ void gl_lds16(const uint4* g, uint4* l) {
    __builtin_amdgcn_global_load_lds(
        (const __attribute__((address_space(1))) void*)g,
        (__attribute__((address_space(3))) void*)l, 16, 0, 0);
}

// ---------------------------------------------------------------------------
// Fused prep (one launch):
//  blocks [0,256)   : split X into blocked hi/lo  (granule = L*128 + r per 128-row block)
//  blocks [256,320) : split E into blocked hi/lo  (granule = L*256 + c per 256-code tile)
//  blocks [320,2368): esqb[k] = ||e_k||^2 + 1024; packed[] init
// ---------------------------------------------------------------------------
__global__ __launch_bounds__(256)
void prep_kernel(const float* __restrict__ X, const float* __restrict__ E,
                 uint4* __restrict__ Xh, uint4* __restrict__ Xl,
                 uint4* __restrict__ Eh, uint4* __restrict__ El,
                 float* __restrict__ esqb, unsigned long long* __restrict__ packed) {
    const int tid = threadIdx.x;
    const int bid = blockIdx.x;
    if (bid < 256) {
        const int rb = bid;
#pragma unroll 1
        for (int it = 0; it < 16; ++it) {
            const int idx = it * 256 + tid;          // L*128 + r
            const int r = idx & 127, L = idx >> 7;
            const float* p = X + (size_t)(rb * 128 + r) * D_DIM + L * 8;
            const float4 a = *(const float4*)p, b = *(const float4*)(p + 4);
            uint4 hi, lo; cvt_granule(a, b, hi, lo);
            Xh[rb * 4096 + idx] = hi; Xl[rb * 4096 + idx] = lo;
        }
    } else if (bid < 320) {
        const int cbk = bid - 256;
#pragma unroll 1
        for (int it = 0; it < 16; ++it) {
            const int g = cbk * 4096 + it * 256 + tid;   // flat granule
            const int cb = g >> 13, rem = g & 8191;
            const int L = rem >> 8, c = rem & 255;
            const float* p = E + (size_t)(cb * 256 + c) * D_DIM + L * 8;
            const float4 a = *(const float4*)p, b = *(const float4*)(p + 4);
            uint4 hi, lo; cvt_granule(a, b, hi, lo);
            Eh[g] = hi; El[g] = lo;
        }
    } else {
        const int t = (bid - 320) * 256 + tid;
        if (t < N_ROWS) packed[t] = ~0ull;
        const int gw   = t >> 6;
        const int lane = t & 63;
        const float4 v = ((const float4*)(E + (size_t)gw * D_DIM))[lane];
        float s = v.x * v.x + v.y * v.y + v.z * v.z + v.w * v.w;
#pragma unroll
        for (int off = 32; off; off >>= 1) s += __shfl_down(s, off, 64);
        if (lane == 0) esqb[gw] = s + 1024.0f;
    }
}

// ---------------------------------------------------------------------------
// Main: flat 256-iteration software pipeline, double-buffered LDS.
// Iteration it = (ct, dc): issue global_load_lds for it+1 into buf^1,
// compute it from buf^0 (24 MFMA, 12 ds_read_b128), one barrier.
// The barrier's vmcnt(0) drain now waits on loads issued a full compute
// phase earlier (~1.5 kcyc slack vs ~0.9 kcyc delivery) -> drain ~ 0.
// ---------------------------------------------------------------------------
__global__ __launch_bounds__(256, 2)
void vq_mfma3_kernel(const uint4* __restrict__ Xh, const uint4* __restrict__ Xl,
                     const uint4* __restrict__ Eh, const uint4* __restrict__ El,
                     const float* __restrict__ esqb,
                     unsigned long long* __restrict__ packed) {
    __shared__ uint4 sXh[2][256], sXl[2][256];   // 2 x 4 KB each
    __shared__ uint4 sEh[2][512], sEl[2][512];   // 2 x 8 KB each -> 48 KB total

    const int tid  = threadIdx.x;
    const int lane = tid & 63;
    const int wv   = tid >> 6;
    const int wr   = wv >> 1, wc = wv & 1;
    const int l31  = lane & 31;
    const int lh   = lane >> 5;
    const int wbase = wv << 6;            // wave-uniform LDS granule base
    const int bx   = blockIdx.x;
    const int cs0  = blockIdx.y * STRIP;

    const uint4* Xhb = Xh + bx * 4096;
    const uint4* Xlb = Xl + bx * 4096;
    const uint4* Ehs = Eh + (size_t)blockIdx.y * NCT * 8192;
    const uint4* Els = El + (size_t)blockIdx.y * NCT * 8192;

    float best[2][16];
    int   bidx[2][16];
#pragma unroll
    for (int ti = 0; ti < 2; ++ti)
#pragma unroll
        for (int r = 0; r < 16; ++r) { best[ti][r] = 3.0e38f; bidx[ti][r] = 0; }

    f32x16 acc[2][4];

    // prime the pipeline: loads for it=0 into buf 0
    {
        gl_lds16(Xhb + tid, &sXh[0][wbase]);
        gl_lds16(Xlb + tid, &sXl[0][wbase]);
#pragma unroll
        for (int i = 0; i < 2; ++i) gl_lds16(Ehs + i * 256 + tid, &sEh[0][i * 256 + wbase]);
#pragma unroll
        for (int i = 0; i < 2; ++i) gl_lds16(Els + i * 256 + tid, &sEl[0][i * 256 + wbase]);
    }
    __syncthreads();

#pragma unroll 1
    for (int it = 0; it < NIT; ++it) {
        const int b = it & 1;

        // ---- issue loads for it+1 into buf b^1 ----
        const int nit = it + 1;
        if (nit < NIT) {
            const int nct = nit >> 4, ndc = nit & 15;
            const int nb = nit & 1;
            const uint4* xs = Xhb + ndc * 256;
            const uint4* xl = Xlb + ndc * 256;
            const uint4* es = Ehs + nct * 8192 + ndc * 512;
            const uint4* el = Els + nct * 8192 + ndc * 512;
            gl_lds16(xs + tid, &sXh[nb][wbase]);
            gl_lds16(xl + tid, &sXl[nb][wbase]);
#pragma unroll
            for (int i = 0; i < 2; ++i) gl_lds16(es + i * 256 + tid, &sEh[nb][i * 256 + wbase]);
#pragma unroll
            for (int i = 0; i < 2; ++i) gl_lds16(el + i * 256 + tid, &sEl[nb][i * 256 + wbase]);
        }

        // ---- reset acc at code-tile start ----
        if ((it & 15) == 0) {
#pragma unroll
            for (int ti = 0; ti < 2; ++ti)
#pragma unroll
                for (int tj = 0; tj < 4; ++tj)
#pragma unroll
                    for (int i = 0; i < 16; ++i) acc[ti][tj][i] = 0.0f;
        }

        // ---- compute chunk it from buf b: one K-step of 16 dims ----
        {
            f16x8 a0[2], a1[2], b0[4], b1[4];
#pragma unroll
            for (int ti = 0; ti < 2; ++ti) {
                const int o = lh * 128 + wr * 64 + ti * 32 + l31;
                a0[ti] = __builtin_bit_cast(f16x8, sXh[b][o]);
                a1[ti] = __builtin_bit_cast(f16x8, sXl[b][o]);
            }
#pragma unroll
            for (int tj = 0; tj < 4; ++tj) {
                const int o = lh * 256 + wc * 128 + tj * 32 + l31;
                b0[tj] = __builtin_bit_cast(f16x8, sEh[b][o]);
                b1[tj] = __builtin_bit_cast(f16x8, sEl[b][o]);
            }
#pragma unroll
            for (int ti = 0; ti < 2; ++ti)
#pragma unroll
                for (int tj = 0; tj < 4; ++tj)
                    acc[ti][tj] = MFMA32(a1[ti], b0[tj], acc[ti][tj]);   // xl*eh
#pragma unroll
            for (int ti = 0; ti < 2; ++ti)
#pragma unroll
                for (int tj = 0; tj < 4; ++tj)
                    acc[ti][tj] = MFMA32(a0[ti], b1[tj], acc[ti][tj]);   // xh*el
#pragma unroll
            for (int ti = 0; ti < 2; ++ti)
#pragma unroll
                for (int tj = 0; tj < 4; ++tj)
                    acc[ti][tj] = MFMA32(a0[ti], b0[tj], acc[ti][tj]);   // xh*eh
        }

        // ---- epilogue at code-tile end: distances + running argmin ----
        if ((it & 15) == 15) {
            const int ct = it >> 4;
#pragma unroll
            for (int tj = 0; tj < 4; ++tj) {
                const int code = cs0 + ct * BN + wc * 128 + tj * 32 + l31;
                const float eb = esqb[code];     // esq + 1024
#pragma unroll
                for (int ti = 0; ti < 2; ++ti)
#pragma unroll
                    for (int r = 0; r < 16; ++r) {
                        const float dv = fmaf(-2.0f, acc[ti][tj][r], eb);
                        if (dv < best[ti][r]) { best[ti][r] = dv; bidx[ti][r] = code; }
                    }
            }
        }

        __syncthreads();   // drain: it+1's loads had a full compute phase of slack
    }

    // ---- butterfly over the 32 code-lanes, then device atomicMin ----
#pragma unroll
    for (int ti = 0; ti < 2; ++ti)
#pragma unroll
        for (int r = 0; r < 16; ++r) {
            float b = best[ti][r]; int bi = bidx[ti][r];
#pragma unroll
            for (int m = 16; m >= 1; m >>= 1) {
                const float ov = __shfl_xor(b, m, 32);
                const int   oi = __shfl_xor(bi, m, 32);
                if (ov < b || (ov == b && oi < bi)) { b = ov; bi = oi; }
            }
            if (l31 == 0) {
                const int row = bx * BM + wr * 64 + ti * 32 + (r & 3) + 8 * (r >> 2) + 4 * lh;
                const unsigned long long p =
                    ((unsigned long long)__float_as_uint(b) << 32) | (unsigned)bi;
                atomicMin(&packed[row], p);
            }
        }
}

// ---------------------------------------------------------------------------
// Fallback (round-4 verified kernel): in-loop split, for small ws_size.
// ---------------------------------------------------------------------------
__global__ void prologue_fb(const float* __restrict__ E, float* __restrict__ esqb,
                            unsigned long long* __restrict__ packed) {
    const int t = blockIdx.x * 256 + threadIdx.x;
    if (t < N_ROWS) packed[t] = ~0ull;
    const int gw = t >> 6, lane = t & 63;
    const float4 v = ((const float4*)(E + (size_t)gw * D_DIM))[lane];
    float s = v.x * v.x + v.y * v.y + v.z * v.z + v.w * v.w;
#pragma unroll
    for (int off = 32; off; off >>= 1) s += __shfl_down(s, off, 64);
    if (lane == 0) esqb[gw] = s + 1024.0f;
}

__global__ __launch_bounds__(256, 2)
void vq_mfma_fallback(const float* __restrict__ X, const float* __restrict__ E,
                      const float* __restrict__ esqb,
                      unsigned long long* __restrict__ packed) {
    __shared__ uint4 fXh[128 * 8], fXl[128 * 8];
    __shared__ uint4 fEh[128 * 8], fEl[128 * 8];
    __shared__ float fEsq[2048];

    const int tid  = threadIdx.x;
    const int lane = tid & 63;
    const int wv   = tid >> 6;
    const int wr   = wv >> 1, wc = wv & 1;
    const int l31  = lane & 31;
    const int lh   = lane >> 5;
    const int row0 = blockIdx.x * 128;
    const int cs0  = blockIdx.y * 2048;

#pragma unroll
    for (int i = 0; i < 8; ++i) fEsq[tid + 256 * i] = esqb[cs0 + tid + 256 * i];

    const int sr = tid >> 3, sg = tid & 7;

    float best[2][16]; int bidx[2][16];
#pragma unroll
    for (int ti = 0; ti < 2; ++ti)
#pragma unroll
        for (int r = 0; r < 16; ++r) { best[ti][r] = 3.0e38f; bidx[ti][r] = 0; }

    f32x16 acc[2][2];

#pragma unroll 1
    for (int ct = 0; ct < 16; ++ct) {
#pragma unroll
        for (int ti = 0; ti < 2; ++ti)
#pragma unroll
            for (int tj = 0; tj < 2; ++tj)
#pragma unroll
                for (int i = 0; i < 16; ++i) acc[ti][tj][i] = 0.0f;

#pragma unroll 1
        for (int dc = 0; dc < 4; ++dc) {
            __syncthreads();
#pragma unroll
            for (int i = 0; i < 4; ++i) {
                const int r = 32 * i + sr;
                const float* p = X + (size_t)(row0 + r) * D_DIM + dc * 64 + sg * 8;
                const float4 a = *(const float4*)p, b = *(const float4*)(p + 4);
                uint4 hi, lo; cvt_granule(a, b, hi, lo);
                const int o = r * 8 + (sg ^ (r & 7));
                fXh[o] = hi; fXl[o] = lo;
            }
#pragma unroll
            for (int i = 0; i < 4; ++i) {
                const int r = 32 * i + sr;
                const float* p = E + (size_t)(cs0 + ct * 128 + r) * D_DIM + dc * 64 + sg * 8;
                const float4 a = *(const float4*)p, b = *(const float4*)(p + 4);
                uint4 hi, lo; cvt_granule(a, b, hi, lo);
                const int o = r * 8 + (sg ^ (r & 7));
                fEh[o] = hi; fEl[o] = lo;
            }
            __syncthreads();

#pragma unroll
            for (int s = 0; s < 4; ++s) {
                const int gi = s * 2 + lh;
                f16x8 axh[2], axl[2], beh[2], bel[2];
#pragma unroll
                for (int ti = 0; ti < 2; ++ti) {
                    const int r = wr * 64 + ti * 32 + l31;
                    const int o = r * 8 + (gi ^ (r & 7));
                    axh[ti] = __builtin_bit_cast(f16x8, fXh[o]);
                    axl[ti] = __builtin_bit_cast(f16x8, fXl[o]);
                }
#pragma unroll
                for (int tj = 0; tj < 2; ++tj) {
                    const int c = wc * 64 + tj * 32 + l31;
                    const int o = c * 8 + (gi ^ (c & 7));
                    beh[tj] = __builtin_bit_cast(f16x8, fEh[o]);
                    bel[tj] = __builtin_bit_cast(f16x8, fEl[o]);
                }
#pragma unroll
                for (int ti = 0; ti < 2; ++ti)
#pragma unroll
                    for (int tj = 0; tj < 2; ++tj) {
                        acc[ti][tj] = MFMA32(axl[ti], beh[tj], acc[ti][tj]);
                        acc[ti][tj] = MFMA32(axh[ti], bel[tj], acc[ti][tj]);
                        acc[ti][tj] = MFMA32(axh[ti], beh[tj], acc[ti][tj]);
                    }
            }
        }

#pragma unroll
        for (int tj = 0; tj < 2; ++tj) {
            const int cloc = ct * 128 + wc * 64 + tj * 32 + l31;
            const float eb = fEsq[cloc];
            const int  code = cs0 + cloc;
#pragma unroll
            for (int ti = 0; ti < 2; ++ti)
#pragma unroll
                for (int r = 0; r < 16; ++r) {
                    const float dv = fmaf(-2.0f, acc[ti][tj][r], eb);
                    if (dv < best[ti][r]) { best[ti][r] = dv; bidx[ti][r] = code; }
                }
        }
    }

#pragma unroll
    for (int ti = 0; ti < 2; ++ti)
#pragma unroll
        for (int r = 0; r < 16; ++r) {
            float b = best[ti][r]; int bi = bidx[ti][r];
#pragma unroll
            for (int m = 16; m >= 1; m >>= 1) {
                const float ov = __shfl_xor(b, m, 32);
                const int   oi = __shfl_xor(bi, m, 32);
                if (ov < b || (ov == b && oi < bi)) { b = ov; bi = oi; }
            }
            if (l31 == 0) {
                const int row = row0 + wr * 64 + ti * 32 + (r & 3) + 8 * (r >> 2) + 4 * lh;
                const unsigned long long p =
                    ((unsigned long long)__float_as_uint(b) << 32) | (unsigned)bi;
                atomicMin(&packed[row], p);
            }
        }
}

// ---------------------------------------------------------------------------
__global__ void finish_kernel(const unsigned long long* __restrict__ packed,
                              int* __restrict__ out) {
    const int i = blockIdx.x * 256 + threadIdx.x;
    out[i] = (int)(unsigned)(packed[i] & 0xffffffffull);
}

// ---------------------------------------------------------------------------
extern "C" void kernel_launch(void* const* d_in, const int* in_sizes, int n_in,
                              void* d_out, int out_size, void* d_ws, size_t ws_size,
                              hipStream_t stream) {
    const float* X = (const float*)d_in[0];    // [32768, 256]
    const float* E = (const float*)d_in[1];    // [8192, 256]
    char* ws = (char*)d_ws;
    float* esqb = (float*)ws;                                        // 32 KB
    unsigned long long* packed = (unsigned long long*)(ws + 32768);  // 256 KB
    int* out = (int*)d_out;

    const size_t base = 294912;                       // 32 KB + 256 KB, 16B-aligned
    const size_t szX  = (size_t)N_ROWS * D_DIM * 2;   // 16 MB per half
    const size_t szE  = (size_t)K_CODES * D_DIM * 2;  // 4 MB per half
    const size_t need = base + 2 * szX + 2 * szE;

    if (ws_size >= need) {
        uint4* Xh = (uint4*)(ws + base);
        uint4* Xl = (uint4*)(ws + base + szX);
        uint4* Eh = (uint4*)(ws + base + 2 * szX);
        uint4* El = (uint4*)(ws + base + 2 * szX + szE);
        prep_kernel<<<dim3(2368), dim3(256), 0, stream>>>(X, E, Xh, Xl, Eh, El, esqb, packed);
        vq_mfma3_kernel<<<dim3(N_ROWS / BM, NSTRIP), dim3(256), 0, stream>>>(
            Xh, Xl, Eh, El, esqb, packed);
    } else {
        prologue_fb<<<dim3(2048), dim3(256), 0, stream>>>(E, esqb, packed);
        vq_mfma_fallback<<<dim3(N_ROWS / 128, 4), dim3(256), 0, stream>>>(X, E, esqb, packed);
    }

    finish_kernel<<<dim3(N_ROWS / 256), dim3(256), 0, stream>>>(packed, out);
}